// Round 20
// baseline (192.069 us; speedup 1.0000x reference)
//
#include <hip/hip_runtime.h>
#include <math.h>

typedef __attribute__((ext_vector_type(8))) short bf16x8;
typedef __attribute__((ext_vector_type(16))) float f32x16;

#define GAT_ALPHA 0.2f

// raw barrier: LDS ops drained, but VMEM loads stay in flight (no vmcnt(0))
#define SOFT_BARRIER() do { \
    asm volatile("s_waitcnt lgkmcnt(0)" ::: "memory"); \
    __builtin_amdgcn_s_barrier(); \
} while (0)

static __device__ __forceinline__ unsigned short f2bf(float x) {
    unsigned u = __float_as_uint(x);
    u += 0x7fffu + ((u >> 16) & 1u);
    return (unsigned short)(u >> 16);
}
static __device__ __forceinline__ float bf2f(unsigned short b) {
    return __uint_as_float(((unsigned)b) << 16);
}

// ---------------- k_prep: h = input @ W (f32), per-row {rowsum, ss=h.c2, sd=h.c1}
__global__ __launch_bounds__(512)
void k_prep(const float* __restrict__ input, const float* __restrict__ W,
            const float* __restrict__ c1, const float* __restrict__ c2,
            unsigned short* __restrict__ hb, float* __restrict__ ssx,
            float* __restrict__ sd, int N, int Fin, int Fout)
{
    __shared__ float in_lds[4][256];
    __shared__ float red[4][3];
    const int tid = threadIdx.x;
    const int r0 = blockIdx.x * 4;
    for (int idx = tid; idx < 4 * Fin; idx += 512) {
        int r = idx / Fin, c = idx - r * Fin;
        in_lds[r][c] = input[(size_t)(r0 + r) * Fin + c];
    }
    if (tid < 12) ((float*)red)[tid] = 0.f;
    __syncthreads();
    const int y = tid >> 7, f = tid & 127;
    float acc = 0.f;
    for (int k = 0; k < Fin; ++k)
        acc = fmaf(in_lds[y][k], W[(size_t)k * Fout + f], acc);
    const int row = r0 + y;
    hb[(size_t)row * Fout + f] = f2bf(acc);
    float rs = acc, sv = acc * c2[f], dv = acc * c1[f];
    for (int off = 32; off > 0; off >>= 1) {
        rs += __shfl_xor(rs, off);
        sv += __shfl_xor(sv, off);
        dv += __shfl_xor(dv, off);
    }
    if ((tid & 63) == 0) {
        atomicAdd(&red[y][0], rs);
        atomicAdd(&red[y][1], sv);
        atomicAdd(&red[y][2], dv);
    }
    __syncthreads();
    if (f == 0) {
        float rsum = red[y][0];
        ssx[row] = (rsum != 0.f) ? red[y][1] : -1e30f;  // fold j-mask into score
        sd[row]  = red[y][2];
    }
}

// ---------------- k_smax: global masked max of ssx
__global__ __launch_bounds__(1024)
void k_smax(const float* __restrict__ ssx, float* __restrict__ smax, int N)
{
    __shared__ float red[16];
    const int tid = threadIdx.x;
    float m = -3e38f;
    for (int i = tid; i < N; i += 1024) m = fmaxf(m, ssx[i]);
    for (int off = 32; off > 0; off >>= 1) m = fmaxf(m, __shfl_xor(m, off));
    if ((tid & 63) == 0) red[tid >> 6] = m;
    __syncthreads();
    if (tid == 0) {
        float mm = red[0];
        for (int i = 1; i < 16; ++i) mm = fmaxf(mm, red[i]);
        smax[0] = mm;
    }
}

// ---------------- k_transpose: hb [N][Fout] -> ht [Fout][N]
__global__ __launch_bounds__(256)
void k_transpose(const unsigned short* __restrict__ hb, unsigned short* __restrict__ ht,
                 int N, int Fout)
{
    __shared__ unsigned short t[64][65];
    const int bx = blockIdx.x;
    const int by = blockIdx.y;
    const int tid = threadIdx.x;
    for (int i = 0; i < 16; ++i) {
        int idx = i * 256 + tid; int r = idx >> 6, c = idx & 63;
        t[r][c] = hb[(size_t)(bx * 64 + r) * Fout + by * 64 + c];
    }
    __syncthreads();
    for (int i = 0; i < 16; ++i) {
        int idx = i * 256 + tid; int r = idx >> 6, c = idx & 63;
        ht[(size_t)(by * 64 + r) * N + bx * 64 + c] = t[c][r];
    }
}

// ---------------- k_attn<JCH>: grid (M/128, N/JCH), 256 thr (4 waves x 32 rows).
// R19 structure; launch_bounds (256,4): 4 blocks/CU (16 waves) -- VGPR ~84
// fits the 128 cap, LDS 36.8KB x4 = 147KB <= 160KB. More TLP to cover the
// adj-stream latency under the 2-deep prefetch.
template<int JCH>
__global__ __launch_bounds__(256, 4)
void k_attn(const int* __restrict__ adj, const unsigned short* __restrict__ ht,
            const float* __restrict__ ssx, const float* __restrict__ sd,
            const float* __restrict__ smaxp, unsigned short* __restrict__ part,
            float* __restrict__ dpart, int N, int M)
{
    constexpr int NCH = JCH / 64;     // 64-j chunks
    constexpr int KSG = JCH / 16;     // total K16 steps
    __shared__ char btile[2][16384];  // [f 0..127][slot 0..7 x16B], src pre-swizzled
    __shared__ float sxl[JCH];

    const int tid = threadIdx.x;
    const int bi = blockIdx.x, bj = blockIdx.y;
    const int rb = bi * 128;
    const int j0 = bj * JCH;

    for (int i = tid * 4; i < JCH; i += 1024)
        *(float4*)&sxl[i] = *(const float4*)(ssx + j0 + i);

    const int w = tid >> 6, l = tid & 63;
    const int col = l & 31, hi = l >> 5;
    const int row = rb + w * 32 + col;
    const float s0 = sd[row];
    const float vb = s0 + smaxp[0];
    const float m0 = fmaxf(vb, GAT_ALPHA * vb);   // leakyrelu of max valid score

    // ---- staging roles: 4 x 16B per thread per chunk, linear LDS dest,
    // source pre-swizzled so read side can XOR (slot q reads j-group q^(f&7))
    const int L0 = 0 * 256 + tid, L1 = 1 * 256 + tid, L2 = 2 * 256 + tid, L3 = 3 * 256 + tid;
    const unsigned short* sp0 = ht + (size_t)(L0 >> 3) * N + j0 + (((L0 & 7) ^ ((L0 >> 3) & 7)) << 3);
    const unsigned short* sp1 = ht + (size_t)(L1 >> 3) * N + j0 + (((L1 & 7) ^ ((L1 >> 3) & 7)) << 3);
    const unsigned short* sp2 = ht + (size_t)(L2 >> 3) * N + j0 + (((L2 & 7) ^ ((L2 >> 3) & 7)) << 3);
    const unsigned short* sp3 = ht + (size_t)(L3 >> 3) * N + j0 + (((L3 & 7) ^ ((L3 >> 3) & 7)) << 3);

    // ---- adj per-lane stream: 32B per kstep (int4 pair), 2-deep flat prefetch
    const int* __restrict__ abase = adj + (size_t)row * N + j0 + hi * 8;
    int4 cA0 = *(const int4*)(abase);
    int4 cA1 = *(const int4*)(abase + 4);
    int4 cB0 = *(const int4*)(abase + 16);
    int4 cB1 = *(const int4*)(abase + 20);

    // B-read offsets
    const int rswz = col & 7;
    const char* const bb0 = (const char*)btile + (col + 0)  * 128;
    const char* const bb1 = (const char*)btile + (col + 32) * 128;
    const char* const bb2 = (const char*)btile + (col + 64) * 128;
    const char* const bb3 = (const char*)btile + (col + 96) * 128;

    f32x16 acc0 = {0,0,0,0,0,0,0,0,0,0,0,0,0,0,0,0};
    f32x16 acc1 = {0,0,0,0,0,0,0,0,0,0,0,0,0,0,0,0};
    f32x16 acc2 = {0,0,0,0,0,0,0,0,0,0,0,0,0,0,0,0};
    f32x16 acc3 = {0,0,0,0,0,0,0,0,0,0,0,0,0,0,0,0};
    float d0 = 0.f;

    // prologue: stage chunk 0 -> LDS[0]; issue chunk-1 loads
    bf16x8 rr0 = *(const bf16x8*)(sp0);
    bf16x8 rr1 = *(const bf16x8*)(sp1);
    bf16x8 rr2 = *(const bf16x8*)(sp2);
    bf16x8 rr3 = *(const bf16x8*)(sp3);
    *(bf16x8*)(&btile[0][0] + L0 * 16) = rr0;
    *(bf16x8*)(&btile[0][0] + L1 * 16) = rr1;
    *(bf16x8*)(&btile[0][0] + L2 * 16) = rr2;
    *(bf16x8*)(&btile[0][0] + L3 * 16) = rr3;
    rr0 = *(const bf16x8*)(sp0 + 64);
    rr1 = *(const bf16x8*)(sp1 + 64);
    rr2 = *(const bf16x8*)(sp2 + 64);
    rr3 = *(const bf16x8*)(sp3 + 64);
    SOFT_BARRIER();

    for (int ch = 0; ch < NCH; ++ch) {
        const int par = ch & 1;
        // write staged regs for ch+1 into the opposite buffer (safe: fully
        // consumed at the barrier that ended chunk ch-1)
        if (ch + 1 < NCH) {
            char* wb = &btile[par ^ 1][0];
            *(bf16x8*)(wb + L0 * 16) = rr0;
            *(bf16x8*)(wb + L1 * 16) = rr1;
            *(bf16x8*)(wb + L2 * 16) = rr2;
            *(bf16x8*)(wb + L3 * 16) = rr3;
        }
        // issue loads for ch+2 (land during this chunk's compute)
        if (ch + 2 < NCH) {
            const int o = (ch + 2) * 64;
            rr0 = *(const bf16x8*)(sp0 + o);
            rr1 = *(const bf16x8*)(sp1 + o);
            rr2 = *(const bf16x8*)(sp2 + o);
            rr3 = *(const bf16x8*)(sp3 + o);
        }
        // compute 4 K16-steps from LDS[par] -- prioritized (T5)
        __builtin_amdgcn_s_setprio(1);
        #pragma unroll
        for (int ks = 0; ks < 4; ++ks) {
            const int ksg = ch * 4 + ks;
            int4 u0, u1;
            if ((ks & 1) == 0) { u0 = cA0; u1 = cA1; }
            else               { u0 = cB0; u1 = cB1; }
            // prefetch ksg+2
            {
                const int nk = (ksg + 2 < KSG) ? ksg + 2 : KSG - 1;
                const int* np = abase + nk * 16;
                if ((ks & 1) == 0) { cA0 = *(const int4*)np; cA1 = *(const int4*)(np + 4); }
                else               { cB0 = *(const int4*)np; cB1 = *(const int4*)(np + 4); }
            }
            const float* sx = &sxl[ch * 64 + ks * 16 + hi * 8];
            float4 x0 = *(const float4*)sx;
            float4 x1 = *(const float4*)(sx + 4);
            bf16x8 af;
            {
                unsigned short* pu = (unsigned short*)&af;
                const int* ai0 = (const int*)&u0;
                const int* ai1 = (const int*)&u1;
                const float* f0 = (const float*)&x0;
                const float* f1 = (const float*)&x1;
                float dd = 0.f;
                #pragma unroll
                for (int i = 0; i < 4; ++i) {
                    float v = s0 + f0[i];
                    float a = fmaxf(v, GAT_ALPHA * v);
                    float e = fminf(a - m0, 0.f);
                    float p = (ai0[i] > 0) ? __expf(e) : 0.f;
                    pu[i] = f2bf(p); dd += p;
                }
                #pragma unroll
                for (int i = 0; i < 4; ++i) {
                    float v = s0 + f1[i];
                    float a = fmaxf(v, GAT_ALPHA * v);
                    float e = fminf(a - m0, 0.f);
                    float p = (ai1[i] > 0) ? __expf(e) : 0.f;
                    pu[4 + i] = f2bf(p); dd += p;
                }
                d0 += dd;
            }
            const int soff = par * 16384 + (((ks * 2 + hi) ^ rswz) << 4);
            bf16x8 b0 = *(const bf16x8*)(bb0 + soff);
            bf16x8 b1 = *(const bf16x8*)(bb1 + soff);
            bf16x8 b2 = *(const bf16x8*)(bb2 + soff);
            bf16x8 b3 = *(const bf16x8*)(bb3 + soff);
            acc0 = __builtin_amdgcn_mfma_f32_32x32x16_bf16(af, b0, acc0, 0, 0, 0);
            acc1 = __builtin_amdgcn_mfma_f32_32x32x16_bf16(af, b1, acc1, 0, 0, 0);
            acc2 = __builtin_amdgcn_mfma_f32_32x32x16_bf16(af, b2, acc2, 0, 0, 0);
            acc3 = __builtin_amdgcn_mfma_f32_32x32x16_bf16(af, b3, acc3, 0, 0, 0);
        }
        __builtin_amdgcn_s_setprio(0);
        SOFT_BARRIER();
    }

    // ---- epilogue: denom partial + fragment-major bf16 partials (R13-verified)
    d0 += __shfl_xor(d0, 32);
    if (hi == 0) dpart[(size_t)bj * M + row] = d0;

    unsigned short* pb = part + (size_t)bj * M * 128
                       + (((size_t)(bi * 4 + w) * 256) + l) * 16;
    #define STORE_TILE(A, t) { \
        bf16x8 lo, hic; \
        unsigned short* q0 = (unsigned short*)&lo; \
        unsigned short* q1 = (unsigned short*)&hic; \
        q0[0]=f2bf(A[0]); q0[1]=f2bf(A[1]); q0[2]=f2bf(A[2]); q0[3]=f2bf(A[3]); \
        q0[4]=f2bf(A[4]); q0[5]=f2bf(A[5]); q0[6]=f2bf(A[6]); q0[7]=f2bf(A[7]); \
        q1[0]=f2bf(A[8]); q1[1]=f2bf(A[9]); q1[2]=f2bf(A[10]); q1[3]=f2bf(A[11]); \
        q1[4]=f2bf(A[12]); q1[5]=f2bf(A[13]); q1[6]=f2bf(A[14]); q1[7]=f2bf(A[15]); \
        *(bf16x8*)(pb + (size_t)(t) * 1024) = lo; \
        *(bf16x8*)(pb + (size_t)(t) * 1024 + 8) = hic; }
    STORE_TILE(acc0, 0)
    STORE_TILE(acc1, 1)
    STORE_TILE(acc2, 2)
    STORE_TILE(acc3, 3)
    #undef STORE_TILE
}

// ---------------- k_dsum: denom[r] = sum_s dpart[s][r]
__global__ __launch_bounds__(256)
void k_dsum(const float* __restrict__ dpart, float* __restrict__ denom, int M, int nsp)
{
    const int r = blockIdx.x * 256 + threadIdx.x;
    if (r < M) {
        float d = 0.f;
        for (int s = 0; s < nsp; ++s) d += dpart[(size_t)s * M + r];
        denom[r] = d;
    }
}

// ---------------- k_combine: out = elu( (sum_s part[s]) / denom[row] )
// 32x32 D layout: col = lane&31, row = (reg&3) + 8*(reg>>2) + 4*(lane>>5)
__global__ __launch_bounds__(256)
void k_combine(const unsigned short* __restrict__ part, const float* __restrict__ denom,
               float* __restrict__ out, int M, int nsp)
{
    const int idx = blockIdx.x * 256 + threadIdx.x;   // unit of 8 bf16
    const int s8 = idx & 1;                            // regs 0..7 / 8..15
    const int l  = (idx >> 1) & 63;
    const int t  = (idx >> 7) & 3;
    const int w  = (idx >> 9) & 3;
    const int bi = idx >> 11;
    const int colg = t * 32 + (l & 31);
    const int hi = l >> 5;

    float sums[8] = {0.f, 0.f, 0.f, 0.f, 0.f, 0.f, 0.f, 0.f};
    const unsigned short* p = part + (size_t)idx * 8;
    for (int s = 0; s < nsp; ++s) {
        bf16x8 v = *(const bf16x8*)(p + (size_t)s * M * 128);
        const unsigned short* vp = (const unsigned short*)&v;
        #pragma unroll
        for (int i = 0; i < 8; ++i) sums[i] += bf2f(vp[i]);
    }
    const int rbase = bi * 128 + w * 32 + 4 * hi;
    #pragma unroll
    for (int i = 0; i < 8; ++i) {
        const int reg = s8 * 8 + i;
        const int row = rbase + (reg & 3) + 8 * (reg >> 2);
        const float dd = denom[row];
        const float inv = (dd > 0.f) ? 1.f / dd : 0.f;
        float x = sums[i] * inv;
        x = (x > 0.f) ? x : expm1f(x);
        out[(size_t)row * 128 + colg] = x;
    }
}

extern "C" void kernel_launch(void* const* d_in, const int* in_sizes, int n_in,
                              void* d_out, int out_size, void* d_ws, size_t ws_size,
                              hipStream_t stream)
{
    const float* input = (const float*)d_in[0];
    const float* W     = (const float*)d_in[1];
    const float* c1    = (const float*)d_in[2];
    const float* c2    = (const float*)d_in[3];
    const int*   adj   = (const int*)d_in[4];

    const int Fout = in_sizes[2];
    const int Fin  = in_sizes[1] / Fout;
    const int N    = in_sizes[0] / Fin;
    const int M    = out_size / Fout;
    float* out = (float*)d_out;

    char* ws = (char*)d_ws;
    const size_t o_hb   = 0;
    const size_t o_ht   = o_hb + (size_t)N * Fout * 2;
    const size_t o_ssx  = o_ht + (size_t)N * Fout * 2;
    const size_t o_sd   = o_ssx + (size_t)N * 4;
    const size_t o_smax = o_sd + (size_t)N * 4;
    const size_t o_den  = o_smax + 64;
    const size_t o_dpart = (o_den + (size_t)M * 4 + 63) & ~63ULL;

    const int NS = 8;   // half the blocks/partials of NS=16; part = 16 MB
    const size_t o_part = (o_dpart + (size_t)NS * M * 4 + 63) & ~63ULL;

    unsigned short* hb = (unsigned short*)(ws + o_hb);
    unsigned short* ht = (unsigned short*)(ws + o_ht);
    float* ssx   = (float*)(ws + o_ssx);
    float* sd    = (float*)(ws + o_sd);
    float* smax  = (float*)(ws + o_smax);
    float* denom = (float*)(ws + o_den);
    float* dpart = (float*)(ws + o_dpart);
    unsigned short* part = (unsigned short*)(ws + o_part);

    k_prep<<<N / 4, 512, 0, stream>>>(input, W, c1, c2, hb, ssx, sd, N, Fin, Fout);
    k_smax<<<1, 1024, 0, stream>>>(ssx, smax, N);
    k_transpose<<<dim3(N / 64, Fout / 64), 256, 0, stream>>>(hb, ht, N, Fout);

    k_attn<1024><<<dim3(M / 128, NS), 256, 0, stream>>>(
        adj, ht, ssx, sd, smax, part, dpart, N, M);

    k_dsum<<<(M + 255) / 256, 256, 0, stream>>>(dpart, denom, M, NS);
    k_combine<<<M * Fout / 8 / 256, 256, 0, stream>>>(part, denom, out, M, NS);
}

// Round 21
// 130.737 us; speedup vs baseline: 1.4691x; 1.4691x over previous
//
#include <hip/hip_runtime.h>
#include <math.h>

typedef __attribute__((ext_vector_type(8))) short bf16x8;
typedef __attribute__((ext_vector_type(16))) float f32x16;

#define GAT_ALPHA 0.2f

// raw barrier: LDS ops drained, but VMEM loads stay in flight (no vmcnt(0))
#define SOFT_BARRIER() do { \
    asm volatile("s_waitcnt lgkmcnt(0)" ::: "memory"); \
    __builtin_amdgcn_s_barrier(); \
} while (0)

static __device__ __forceinline__ unsigned short f2bf(float x) {
    unsigned u = __float_as_uint(x);
    u += 0x7fffu + ((u >> 16) & 1u);
    return (unsigned short)(u >> 16);
}
static __device__ __forceinline__ float bf2f(unsigned short b) {
    return __uint_as_float(((unsigned)b) << 16);
}

// ---------------- k_prep: h = input @ W (f32), per-row {rowsum, ss=h.c2, sd=h.c1}
__global__ __launch_bounds__(512)
void k_prep(const float* __restrict__ input, const float* __restrict__ W,
            const float* __restrict__ c1, const float* __restrict__ c2,
            unsigned short* __restrict__ hb, float* __restrict__ ssx,
            float* __restrict__ sd, int N, int Fin, int Fout)
{
    __shared__ float in_lds[4][256];
    __shared__ float red[4][3];
    const int tid = threadIdx.x;
    const int r0 = blockIdx.x * 4;
    for (int idx = tid; idx < 4 * Fin; idx += 512) {
        int r = idx / Fin, c = idx - r * Fin;
        in_lds[r][c] = input[(size_t)(r0 + r) * Fin + c];
    }
    if (tid < 12) ((float*)red)[tid] = 0.f;
    __syncthreads();
    const int y = tid >> 7, f = tid & 127;
    float acc = 0.f;
    for (int k = 0; k < Fin; ++k)
        acc = fmaf(in_lds[y][k], W[(size_t)k * Fout + f], acc);
    const int row = r0 + y;
    hb[(size_t)row * Fout + f] = f2bf(acc);
    float rs = acc, sv = acc * c2[f], dv = acc * c1[f];
    for (int off = 32; off > 0; off >>= 1) {
        rs += __shfl_xor(rs, off);
        sv += __shfl_xor(sv, off);
        dv += __shfl_xor(dv, off);
    }
    if ((tid & 63) == 0) {
        atomicAdd(&red[y][0], rs);
        atomicAdd(&red[y][1], sv);
        atomicAdd(&red[y][2], dv);
    }
    __syncthreads();
    if (f == 0) {
        float rsum = red[y][0];
        ssx[row] = (rsum != 0.f) ? red[y][1] : -1e30f;  // fold j-mask into score
        sd[row]  = red[y][2];
    }
}

// ---------------- k_smax: global masked max of ssx
__global__ __launch_bounds__(1024)
void k_smax(const float* __restrict__ ssx, float* __restrict__ smax, int N)
{
    __shared__ float red[16];
    const int tid = threadIdx.x;
    float m = -3e38f;
    for (int i = tid; i < N; i += 1024) m = fmaxf(m, ssx[i]);
    for (int off = 32; off > 0; off >>= 1) m = fmaxf(m, __shfl_xor(m, off));
    if ((tid & 63) == 0) red[tid >> 6] = m;
    __syncthreads();
    if (tid == 0) {
        float mm = red[0];
        for (int i = 1; i < 16; ++i) mm = fmaxf(mm, red[i]);
        smax[0] = mm;
    }
}

// ---------------- k_transpose: hb [N][Fout] -> ht [Fout][N]
__global__ __launch_bounds__(256)
void k_transpose(const unsigned short* __restrict__ hb, unsigned short* __restrict__ ht,
                 int N, int Fout)
{
    __shared__ unsigned short t[64][65];
    const int bx = blockIdx.x;
    const int by = blockIdx.y;
    const int tid = threadIdx.x;
    for (int i = 0; i < 16; ++i) {
        int idx = i * 256 + tid; int r = idx >> 6, c = idx & 63;
        t[r][c] = hb[(size_t)(bx * 64 + r) * Fout + by * 64 + c];
    }
    __syncthreads();
    for (int i = 0; i < 16; ++i) {
        int idx = i * 256 + tid; int r = idx >> 6, c = idx & 63;
        ht[(size_t)(by * 64 + r) * N + bx * 64 + c] = t[c][r];
    }
}

// ---------------- k_attn<JCH>: grid (M/128, N/JCH), 256 thr (4 waves x 32 rows).
// R19-verified: pipelined loop (dbuf B-tile, 2-deep adj prefetch, soft
// barrier/chunk), T5 setprio around compute, launch_bounds(256,3).
// (256,4) spills: VGPR forced to 64 < 64-reg accumulator -> 97MB scratch (R20).
template<int JCH>
__global__ __launch_bounds__(256, 3)
void k_attn(const int* __restrict__ adj, const unsigned short* __restrict__ ht,
            const float* __restrict__ ssx, const float* __restrict__ sd,
            const float* __restrict__ smaxp, unsigned short* __restrict__ part,
            float* __restrict__ dpart, int N, int M)
{
    constexpr int NCH = JCH / 64;     // 64-j chunks
    constexpr int KSG = JCH / 16;     // total K16 steps
    __shared__ char btile[2][16384];  // [f 0..127][slot 0..7 x16B], src pre-swizzled
    __shared__ float sxl[JCH];

    const int tid = threadIdx.x;
    const int bi = blockIdx.x, bj = blockIdx.y;
    const int rb = bi * 128;
    const int j0 = bj * JCH;

    for (int i = tid * 4; i < JCH; i += 1024)
        *(float4*)&sxl[i] = *(const float4*)(ssx + j0 + i);

    const int w = tid >> 6, l = tid & 63;
    const int col = l & 31, hi = l >> 5;
    const int row = rb + w * 32 + col;
    const float s0 = sd[row];
    const float vb = s0 + smaxp[0];
    const float m0 = fmaxf(vb, GAT_ALPHA * vb);   // leakyrelu of max valid score

    // ---- staging roles: 4 x 16B per thread per chunk, linear LDS dest,
    // source pre-swizzled so read side can XOR (slot q reads j-group q^(f&7))
    const int L0 = 0 * 256 + tid, L1 = 1 * 256 + tid, L2 = 2 * 256 + tid, L3 = 3 * 256 + tid;
    const unsigned short* sp0 = ht + (size_t)(L0 >> 3) * N + j0 + (((L0 & 7) ^ ((L0 >> 3) & 7)) << 3);
    const unsigned short* sp1 = ht + (size_t)(L1 >> 3) * N + j0 + (((L1 & 7) ^ ((L1 >> 3) & 7)) << 3);
    const unsigned short* sp2 = ht + (size_t)(L2 >> 3) * N + j0 + (((L2 & 7) ^ ((L2 >> 3) & 7)) << 3);
    const unsigned short* sp3 = ht + (size_t)(L3 >> 3) * N + j0 + (((L3 & 7) ^ ((L3 >> 3) & 7)) << 3);

    // ---- adj per-lane stream: 32B per kstep (int4 pair), 2-deep flat prefetch
    const int* __restrict__ abase = adj + (size_t)row * N + j0 + hi * 8;
    int4 cA0 = *(const int4*)(abase);
    int4 cA1 = *(const int4*)(abase + 4);
    int4 cB0 = *(const int4*)(abase + 16);
    int4 cB1 = *(const int4*)(abase + 20);

    // B-read offsets
    const int rswz = col & 7;
    const char* const bb0 = (const char*)btile + (col + 0)  * 128;
    const char* const bb1 = (const char*)btile + (col + 32) * 128;
    const char* const bb2 = (const char*)btile + (col + 64) * 128;
    const char* const bb3 = (const char*)btile + (col + 96) * 128;

    f32x16 acc0 = {0,0,0,0,0,0,0,0,0,0,0,0,0,0,0,0};
    f32x16 acc1 = {0,0,0,0,0,0,0,0,0,0,0,0,0,0,0,0};
    f32x16 acc2 = {0,0,0,0,0,0,0,0,0,0,0,0,0,0,0,0};
    f32x16 acc3 = {0,0,0,0,0,0,0,0,0,0,0,0,0,0,0,0};
    float d0 = 0.f;

    // prologue: stage chunk 0 -> LDS[0]; issue chunk-1 loads
    bf16x8 rr0 = *(const bf16x8*)(sp0);
    bf16x8 rr1 = *(const bf16x8*)(sp1);
    bf16x8 rr2 = *(const bf16x8*)(sp2);
    bf16x8 rr3 = *(const bf16x8*)(sp3);
    *(bf16x8*)(&btile[0][0] + L0 * 16) = rr0;
    *(bf16x8*)(&btile[0][0] + L1 * 16) = rr1;
    *(bf16x8*)(&btile[0][0] + L2 * 16) = rr2;
    *(bf16x8*)(&btile[0][0] + L3 * 16) = rr3;
    rr0 = *(const bf16x8*)(sp0 + 64);
    rr1 = *(const bf16x8*)(sp1 + 64);
    rr2 = *(const bf16x8*)(sp2 + 64);
    rr3 = *(const bf16x8*)(sp3 + 64);
    SOFT_BARRIER();

    for (int ch = 0; ch < NCH; ++ch) {
        const int par = ch & 1;
        // write staged regs for ch+1 into the opposite buffer (safe: fully
        // consumed at the barrier that ended chunk ch-1)
        if (ch + 1 < NCH) {
            char* wb = &btile[par ^ 1][0];
            *(bf16x8*)(wb + L0 * 16) = rr0;
            *(bf16x8*)(wb + L1 * 16) = rr1;
            *(bf16x8*)(wb + L2 * 16) = rr2;
            *(bf16x8*)(wb + L3 * 16) = rr3;
        }
        // issue loads for ch+2 (land during this chunk's compute)
        if (ch + 2 < NCH) {
            const int o = (ch + 2) * 64;
            rr0 = *(const bf16x8*)(sp0 + o);
            rr1 = *(const bf16x8*)(sp1 + o);
            rr2 = *(const bf16x8*)(sp2 + o);
            rr3 = *(const bf16x8*)(sp3 + o);
        }
        // compute 4 K16-steps from LDS[par] -- prioritized (T5)
        __builtin_amdgcn_s_setprio(1);
        #pragma unroll
        for (int ks = 0; ks < 4; ++ks) {
            const int ksg = ch * 4 + ks;
            int4 u0, u1;
            if ((ks & 1) == 0) { u0 = cA0; u1 = cA1; }
            else               { u0 = cB0; u1 = cB1; }
            // prefetch ksg+2
            {
                const int nk = (ksg + 2 < KSG) ? ksg + 2 : KSG - 1;
                const int* np = abase + nk * 16;
                if ((ks & 1) == 0) { cA0 = *(const int4*)np; cA1 = *(const int4*)(np + 4); }
                else               { cB0 = *(const int4*)np; cB1 = *(const int4*)(np + 4); }
            }
            const float* sx = &sxl[ch * 64 + ks * 16 + hi * 8];
            float4 x0 = *(const float4*)sx;
            float4 x1 = *(const float4*)(sx + 4);
            bf16x8 af;
            {
                unsigned short* pu = (unsigned short*)&af;
                const int* ai0 = (const int*)&u0;
                const int* ai1 = (const int*)&u1;
                const float* f0 = (const float*)&x0;
                const float* f1 = (const float*)&x1;
                float dd = 0.f;
                #pragma unroll
                for (int i = 0; i < 4; ++i) {
                    float v = s0 + f0[i];
                    float a = fmaxf(v, GAT_ALPHA * v);
                    float e = fminf(a - m0, 0.f);
                    float p = (ai0[i] > 0) ? __expf(e) : 0.f;
                    pu[i] = f2bf(p); dd += p;
                }
                #pragma unroll
                for (int i = 0; i < 4; ++i) {
                    float v = s0 + f1[i];
                    float a = fmaxf(v, GAT_ALPHA * v);
                    float e = fminf(a - m0, 0.f);
                    float p = (ai1[i] > 0) ? __expf(e) : 0.f;
                    pu[4 + i] = f2bf(p); dd += p;
                }
                d0 += dd;
            }
            const int soff = par * 16384 + (((ks * 2 + hi) ^ rswz) << 4);
            bf16x8 b0 = *(const bf16x8*)(bb0 + soff);
            bf16x8 b1 = *(const bf16x8*)(bb1 + soff);
            bf16x8 b2 = *(const bf16x8*)(bb2 + soff);
            bf16x8 b3 = *(const bf16x8*)(bb3 + soff);
            acc0 = __builtin_amdgcn_mfma_f32_32x32x16_bf16(af, b0, acc0, 0, 0, 0);
            acc1 = __builtin_amdgcn_mfma_f32_32x32x16_bf16(af, b1, acc1, 0, 0, 0);
            acc2 = __builtin_amdgcn_mfma_f32_32x32x16_bf16(af, b2, acc2, 0, 0, 0);
            acc3 = __builtin_amdgcn_mfma_f32_32x32x16_bf16(af, b3, acc3, 0, 0, 0);
        }
        __builtin_amdgcn_s_setprio(0);
        SOFT_BARRIER();
    }

    // ---- epilogue: denom partial + fragment-major bf16 partials (R13-verified)
    d0 += __shfl_xor(d0, 32);
    if (hi == 0) dpart[(size_t)bj * M + row] = d0;

    unsigned short* pb = part + (size_t)bj * M * 128
                       + (((size_t)(bi * 4 + w) * 256) + l) * 16;
    #define STORE_TILE(A, t) { \
        bf16x8 lo, hic; \
        unsigned short* q0 = (unsigned short*)&lo; \
        unsigned short* q1 = (unsigned short*)&hic; \
        q0[0]=f2bf(A[0]); q0[1]=f2bf(A[1]); q0[2]=f2bf(A[2]); q0[3]=f2bf(A[3]); \
        q0[4]=f2bf(A[4]); q0[5]=f2bf(A[5]); q0[6]=f2bf(A[6]); q0[7]=f2bf(A[7]); \
        q1[0]=f2bf(A[8]); q1[1]=f2bf(A[9]); q1[2]=f2bf(A[10]); q1[3]=f2bf(A[11]); \
        q1[4]=f2bf(A[12]); q1[5]=f2bf(A[13]); q1[6]=f2bf(A[14]); q1[7]=f2bf(A[15]); \
        *(bf16x8*)(pb + (size_t)(t) * 1024) = lo; \
        *(bf16x8*)(pb + (size_t)(t) * 1024 + 8) = hic; }
    STORE_TILE(acc0, 0)
    STORE_TILE(acc1, 1)
    STORE_TILE(acc2, 2)
    STORE_TILE(acc3, 3)
    #undef STORE_TILE
}

// ---------------- k_combine: denom-sum fused (verified R17/R18). grid =
// M*128/8/512 blocks; each 256-thr block covers ONE (bi,w) slab = 32 rows.
// 32x32 D layout: col = lane&31, row = (reg&3) + 8*(reg>>2) + 4*(lane>>5)
__global__ __launch_bounds__(256)
void k_combine(const unsigned short* __restrict__ part, const float* __restrict__ dpart,
               float* __restrict__ out, int M, int nsp)
{
    __shared__ float den[32];
    const int tid = threadIdx.x;
    const int base = blockIdx.x * 512;          // first unit of this slab
    const int bi = base >> 11, w = (base >> 9) & 3;
    const int row32 = bi * 128 + w * 32;

    if (tid < 32) {
        float d = 0.f;
        for (int s = 0; s < nsp; ++s) d += dpart[(size_t)s * M + row32 + tid];
        den[tid] = d;
    }
    __syncthreads();

    #pragma unroll
    for (int u = 0; u < 2; ++u) {
        const int idx = base + tid * 2 + u;
        const int s8 = idx & 1;
        const int l  = (idx >> 1) & 63;
        const int t  = (idx >> 7) & 3;
        const int colg = t * 32 + (l & 31);
        const int hi = l >> 5;

        float sums[8] = {0.f, 0.f, 0.f, 0.f, 0.f, 0.f, 0.f, 0.f};
        const unsigned short* p = part + (size_t)idx * 8;
        for (int s = 0; s < nsp; ++s) {
            bf16x8 v = *(const bf16x8*)(p + (size_t)s * M * 128);
            const unsigned short* vp = (const unsigned short*)&v;
            #pragma unroll
            for (int i = 0; i < 8; ++i) sums[i] += bf2f(vp[i]);
        }
        #pragma unroll
        for (int i = 0; i < 8; ++i) {
            const int reg = s8 * 8 + i;
            const int rrel = (reg & 3) + 8 * (reg >> 2) + 4 * hi;
            const float dd = den[rrel];
            const float inv = (dd > 0.f) ? 1.f / dd : 0.f;
            float x = sums[i] * inv;
            x = (x > 0.f) ? x : expm1f(x);
            out[(size_t)(row32 + rrel) * 128 + colg] = x;
        }
    }
}

extern "C" void kernel_launch(void* const* d_in, const int* in_sizes, int n_in,
                              void* d_out, int out_size, void* d_ws, size_t ws_size,
                              hipStream_t stream)
{
    const float* input = (const float*)d_in[0];
    const float* W     = (const float*)d_in[1];
    const float* c1    = (const float*)d_in[2];
    const float* c2    = (const float*)d_in[3];
    const int*   adj   = (const int*)d_in[4];

    const int Fout = in_sizes[2];
    const int Fin  = in_sizes[1] / Fout;
    const int N    = in_sizes[0] / Fin;
    const int M    = out_size / Fout;
    float* out = (float*)d_out;

    char* ws = (char*)d_ws;
    const size_t o_hb   = 0;
    const size_t o_ht   = o_hb + (size_t)N * Fout * 2;
    const size_t o_ssx  = o_ht + (size_t)N * Fout * 2;
    const size_t o_sd   = o_ssx + (size_t)N * 4;
    const size_t o_smax = o_sd + (size_t)N * 4;
    const size_t o_dpart = (o_smax + 64 + 63) & ~63ULL;

    const int NS = 8;   // R19-verified split count; part = 16 MB
    const size_t o_part = (o_dpart + (size_t)NS * M * 4 + 63) & ~63ULL;

    unsigned short* hb = (unsigned short*)(ws + o_hb);
    unsigned short* ht = (unsigned short*)(ws + o_ht);
    float* ssx   = (float*)(ws + o_ssx);
    float* sd    = (float*)(ws + o_sd);
    float* smax  = (float*)(ws + o_smax);
    float* dpart = (float*)(ws + o_dpart);
    unsigned short* part = (unsigned short*)(ws + o_part);

    k_prep<<<N / 4, 512, 0, stream>>>(input, W, c1, c2, hb, ssx, sd, N, Fin, Fout);
    k_smax<<<1, 1024, 0, stream>>>(ssx, smax, N);
    k_transpose<<<dim3(N / 64, Fout / 64), 256, 0, stream>>>(hb, ht, N, Fout);

    k_attn<1024><<<dim3(M / 128, NS), 256, 0, stream>>>(
        adj, ht, ssx, sd, smax, part, dpart, N, M);

    k_combine<<<M * Fout / 8 / 512, 256, 0, stream>>>(part, dpart, out, M, NS);
}